// Round 1
// baseline (108.540 us; speedup 1.0000x reference)
//
#include <hip/hip_runtime.h>
#include <stdint.h>

#define BROWS 16384
#define CDIM  4096
#define NCLS  64
#define BLKLEN 819u

typedef __attribute__((ext_vector_type(4))) float f32x4;
typedef __attribute__((ext_vector_type(8))) short s16x8;           // 8 bf16 (4 VGPRs) - MFMA A/B frag
typedef __attribute__((ext_vector_type(4))) unsigned short u16x4;

// fp32 -> bf16 bits, round-to-nearest-even (avoids header-version issues with __hip_bfloat16)
static __device__ __forceinline__ unsigned short f2bf(float f) {
    union { float f; unsigned u; } v; v.f = f;
    unsigned u = v.u;
    u += 0x7FFFu + ((u >> 16) & 1u);
    return (unsigned short)(u >> 16);
}

// Pre-convert W (64 x 4096 fp32) to bf16 bits in workspace. 65536 float4s.
__global__ __launch_bounds__(256) void convert_w_kernel(const float* __restrict__ W,
                                                        unsigned short* __restrict__ Wb) {
    int i = blockIdx.x * 256 + threadIdx.x;   // 0..65535
    f32x4 v = reinterpret_cast<const f32x4*>(W)[i];
    u16x4 o;
    o[0] = f2bf(v[0]); o[1] = f2bf(v[1]); o[2] = f2bf(v[2]); o[3] = f2bf(v[3]);
    reinterpret_cast<u16x4*>(Wb)[i] = o;
}

// Masked skinny GEMM: out[M=16384, N=64] = mask(x) @ W^T + b
// One wave = 16 rows x 64 cols. Block = 4 waves = 64 rows. Grid = 256 blocks.
template<bool PRECONV>
__global__ __launch_bounds__(256) void dropblock_gemm_kernel(
    const float* __restrict__ x,
    const float* __restrict__ Wf,            // fp32 W (fallback path)
    const unsigned short* __restrict__ Wb,   // bf16 W (fast path)
    const float* __restrict__ bias,
    const int* __restrict__ starts,
    float* __restrict__ out)
{
    const int lane = threadIdx.x & 63;
    const int wv   = threadIdx.x >> 6;       // wave 0..3
    const int l16  = lane & 15;
    const int lg   = lane >> 4;              // 0..3
    const int row_base = blockIdx.x * 64 + wv * 16;

    // A-fragment row for this lane (layout: row = lane&15, k = (lane>>4)*8 + j)
    const int   s    = starts[row_base + l16];
    const int   koff = lg * 8;
    const float* xrow = x + (size_t)(row_base + l16) * CDIM;

    f32x4 acc[4];
    #pragma unroll
    for (int t = 0; t < 4; ++t) acc[t] = (f32x4){0.f, 0.f, 0.f, 0.f};

    #pragma unroll 4
    for (int k0 = 0; k0 < CDIM; k0 += 32) {
        const int c0 = k0 + koff;
        f32x4 xa = *reinterpret_cast<const f32x4*>(xrow + c0);
        f32x4 xb = *reinterpret_cast<const f32x4*>(xrow + c0 + 4);

        const int d0 = c0 - s;               // keep element iff (unsigned)(c - s) >= 819
        s16x8 afrag;
        #pragma unroll
        for (int j = 0; j < 4; ++j) {
            float va = ((unsigned)(d0 + j)     >= BLKLEN) ? xa[j] : 0.f;
            float vb = ((unsigned)(d0 + 4 + j) >= BLKLEN) ? xb[j] : 0.f;
            afrag[j]     = (short)f2bf(va);
            afrag[j + 4] = (short)f2bf(vb);
        }

        #pragma unroll
        for (int t = 0; t < 4; ++t) {
            s16x8 bfrag;
            if (PRECONV) {
                bfrag = *reinterpret_cast<const s16x8*>(Wb + (size_t)(t * 16 + l16) * CDIM + c0);
            } else {
                const float* wrow = Wf + (size_t)(t * 16 + l16) * CDIM + c0;
                f32x4 wa = *reinterpret_cast<const f32x4*>(wrow);
                f32x4 wb = *reinterpret_cast<const f32x4*>(wrow + 4);
                #pragma unroll
                for (int j = 0; j < 4; ++j) {
                    bfrag[j]     = (short)f2bf(wa[j]);
                    bfrag[j + 4] = (short)f2bf(wb[j]);
                }
            }
            acc[t] = __builtin_amdgcn_mfma_f32_16x16x32_bf16(afrag, bfrag, acc[t], 0, 0, 0);
        }
    }

    // Epilogue. C/D layout: col = lane&15, row = (lane>>4)*4 + i
    #pragma unroll
    for (int t = 0; t < 4; ++t) {
        const float bb = bias[t * 16 + l16];
        #pragma unroll
        for (int i = 0; i < 4; ++i) {
            out[(size_t)(row_base + lg * 4 + i) * NCLS + t * 16 + l16] = acc[t][i] + bb;
        }
    }
}

extern "C" void kernel_launch(void* const* d_in, const int* in_sizes, int n_in,
                              void* d_out, int out_size, void* d_ws, size_t ws_size,
                              hipStream_t stream) {
    const float* x      = (const float*)d_in[0];
    const float* W      = (const float*)d_in[1];
    const float* b      = (const float*)d_in[2];
    const int*   starts = (const int*)d_in[3];
    float*       out    = (float*)d_out;

    const size_t wbytes = (size_t)NCLS * CDIM * sizeof(unsigned short);  // 512 KB
    if (ws_size >= wbytes) {
        unsigned short* Wb = (unsigned short*)d_ws;
        convert_w_kernel<<<256, 256, 0, stream>>>(W, Wb);
        dropblock_gemm_kernel<true><<<BROWS / 64, 256, 0, stream>>>(x, W, Wb, b, starts, out);
    } else {
        dropblock_gemm_kernel<false><<<BROWS / 64, 256, 0, stream>>>(x, W, nullptr, b, starts, out);
    }
}